// Round 7
// baseline (752.520 us; speedup 1.0000x reference)
//
#include <hip/hip_runtime.h>
#include <cstdint>

typedef __attribute__((ext_vector_type(8))) short bf16x8;
typedef __attribute__((ext_vector_type(4))) float f32x4;

#define NCELLS_STRIDE 1048576

__device__ __forceinline__ uint32_t bf16_rne(float f) {
    uint32_t u = __float_as_uint(f);
    u += 0x7FFFu + ((u >> 16) & 1u);
    return u >> 16;
}
__device__ __forceinline__ float bf16_f32(uint32_t h) {
    return __uint_as_float(h << 16);
}

__device__ __forceinline__ float tanh_fast(float x) {
    float e = __builtin_amdgcn_exp2f(x * 2.8853900817779268f);
    return fmaf(-2.0f, __builtin_amdgcn_rcpf(e + 1.0f), 1.0f);
}

__device__ __forceinline__ float sel4(float a, float b, float c, float d, int T) {
    float x = (T & 1) ? b : a;
    float y = (T & 1) ? d : c;
    return (T & 2) ? y : x;
}

// ---- prep: W1 (20x64 k-major) -> MFMA A-frag layout, split bf16 hi+lo ----
__global__ __launch_bounds__(256) void prep_kernel(
    const float* __restrict__ W1_0, const float* __restrict__ W1_1,
    const float* __restrict__ W1_2, uint32_t* __restrict__ wf) {
    int m = blockIdx.x;
    const float* W1 = (m == 0) ? W1_0 : (m == 1) ? W1_1 : W1_2;
    int tid = threadIdx.x;
    int Ht = tid >> 6, lane = tid & 63;
    int n = (lane & 15) + 16 * Ht;
    int kb = (lane >> 4) * 8;
    uint32_t dh[4], dl[4];
#pragma unroll
    for (int q = 0; q < 4; ++q) {
        int k0 = kb + 2 * q, k1 = k0 + 1;
        float w0 = (k0 < 20) ? W1[k0 * 64 + n] : 0.0f;
        float w1 = (k1 < 20) ? W1[k1 * 64 + n] : 0.0f;
        uint32_t h0 = bf16_rne(w0), h1 = bf16_rne(w1);
        uint32_t l0 = bf16_rne(w0 - bf16_f32(h0));
        uint32_t l1 = bf16_rne(w1 - bf16_f32(h1));
        dh[q] = h0 | (h1 << 16);
        dl[q] = l0 | (l1 << 16);
    }
    size_t idx = ((size_t)(m * 4 + Ht) * 64 + lane) * 4;
    *(uint4*)(wf + idx)        = make_uint4(dh[0], dh[1], dh[2], dh[3]);
    *(uint4*)(wf + 3072 + idx) = make_uint4(dl[0], dl[1], dl[2], dl[3]);
}

// ---- pass 1: classify (P only), build 4 compacted index lists ----
__global__ __launch_bounds__(256) void pass1_classify(
    const float* __restrict__ P, int* __restrict__ counters,
    int* __restrict__ lists, int N) {
    int i = blockIdx.x * 256 + threadIdx.x;
    bool valid = i < N;
    int ig = valid ? i : N - 1;
    int lane = threadIdx.x & 63;

    const float2* P2 = (const float2*)P + (size_t)ig * 3;
    float2 Pa = P2[0], Pb = P2[1], Pc = P2[2];

    bool flip = Pb.y > Pb.x;
    float rho0 = flip ?  Pa.y :  Pa.x;
    float rho1 = flip ?  Pa.x :  Pa.y;
    float p0f  = flip ?  Pb.y :  Pb.x;
    float p1f  = flip ?  Pb.x :  Pb.y;
    float v0f  = flip ? -Pc.y :  Pc.x;
    float v1f  = flip ? -Pc.x :  Pc.y;

    // cont: exact f64 diffs of f32 values
    double dd0 = fabs((double)rho1 - (double)rho0);
    double dd1 = fabs((double)p1f - (double)p0f);
    double dd2 = fabs((double)v1f - (double)v0f);
    bool cont = fmax(fmax(dd0, dd1), dd2) < 0.005;

    // classification: f32 fast path + eps-guarded exact f64 fallback
    float c0f = __builtin_amdgcn_sqrtf(1.6666666f * p0f * __builtin_amdgcn_rcpf(rho0));
    float c1f = __builtin_amdgcn_sqrtf(1.6666666f * p1f * __builtin_amdgcn_rcpf(rho1));
    float dvf = v1f - v0f;
    float numf = c0f + c1f - (1.0f / 3.0f) * dvf;
    float pz0 = __builtin_amdgcn_exp2f(-0.2f * __builtin_amdgcn_logf(p0f));
    float pz1 = __builtin_amdgcn_exp2f(-0.2f * __builtin_amdgcn_logf(p1f));
    float denf = c0f * pz0 + c1f * pz1;
    float tq = fmaxf(numf * __builtin_amdgcn_rcpf(denf), 1e-8f);
    float t2 = tq * tq;
    float psf = t2 * t2 * tq;
    float pminf = fminf(p0f, p1f);
    float pmaxf = fmaxf(p0f, p1f);
    float csum3 = 3.0f * (c0f + c1f);
    float vs = dvf - csum3;
    int label = (vs >= 0.0f) ? 3 : (psf < pminf ? 1 : (psf > pmaxf ? 0 : 2));

    const float eps = 2e-4f;
    bool amb = (fabsf(psf - pminf) <= eps * pminf) ||
               (fabsf(psf - pmaxf) <= eps * pmaxf) ||
               (fabsf(vs) <= eps * (fabsf(dvf) + csum3));
    if (__builtin_expect(amb, 0)) {
        double r0 = (double)rho0, r1 = (double)rho1;
        double p0 = (double)p0f, p1 = (double)p1f;
        double v0 = (double)v0f, v1 = (double)v1f;
        const double g = 5.0 / 3.0;
        double c0 = sqrt(g * p0 / r0);
        double c1 = sqrt(g * p1 / r1);
        double dv = v1 - v0;
        double z = (g - 1.0) / (2.0 * g);
        double num = c0 + c1 - 0.5 * (g - 1.0) * dv;
        double den = c0 / pow(p0, z) + c1 / pow(p1, z);
        double ps = pow(fmax(num / den, 1e-8), 1.0 / z);
        bool vacd = dv >= 2.0 / (g - 1.0) * (c0 + c1);
        label = vacd ? 3 : (ps < fmin(p0, p1) ? 1 : (ps > fmax(p0, p1) ? 0 : 2));
    }
    int lab = (cont || label == 3) ? 3 : label;   // list 3 = trivial (HLLE or 0)

    // wave-aggregated compaction append
#pragma unroll 1
    for (int l = 0; l < 4; ++l) {
        unsigned long long mask = __ballot(valid && (lab == l));
        int cnt = __popcll(mask);
        if (cnt) {
            int leader = __ffsll(mask) - 1;
            int base = 0;
            if (lane == leader) base = atomicAdd(&counters[l], cnt);
            base = __shfl(base, leader);
            if (valid && lab == l) {
                int pos = base + __popcll(mask & ((1ull << lane) - 1ull));
                lists[(size_t)l * NCELLS_STRIDE + pos] = i;
            }
        }
    }
}

// ---- pass 2: per-list processing (single model per block) ----
__global__ __launch_bounds__(256) void pass2_mlp(
    const float* __restrict__ P, const float* __restrict__ U,
    const float* __restrict__ F, const float* __restrict__ cmax,
    const float* __restrict__ cmin,
    const float* __restrict__ b1_ds, const float* __restrict__ W2_ds, const float* __restrict__ b2_ds,
    const float* __restrict__ b1_dr, const float* __restrict__ W2_dr, const float* __restrict__ b2_dr,
    const float* __restrict__ b1_rs, const float* __restrict__ W2_rs, const float* __restrict__ b2_rs,
    const uint32_t* __restrict__ wf, const int* __restrict__ counters,
    const int* __restrict__ lists,
    float* __restrict__ out, int N) {
    __shared__ __align__(16) uint32_t lds_buf[4][64][20];  // 20.5 KB, staged hi then lo

    int counts[4];
#pragma unroll
    for (int l = 0; l < 4; ++l) counts[l] = counters[l];
    int b = blockIdx.x;
    int list_id = -1, chunk = 0;
#pragma unroll
    for (int l = 0; l < 4; ++l) {
        int ch = (counts[l] + 255) >> 8;
        if (list_id < 0) {
            if (b < ch) { list_id = l; chunk = b; }
            else b -= ch;
        }
    }
    if (list_id < 0) return;
    int cnt = counts[list_id];

    int tid = threadIdx.x;
    int wv = tid >> 6, lane = tid & 63;
    int hi = lane >> 4, lo16 = lane & 15;
    int pos = chunk * 256 + tid;
    bool valid = pos < cnt;
    int gp = valid ? pos : cnt - 1;
    int gi = lists[(size_t)list_id * NCELLS_STRIDE + gp];

    // ---- gather this cell's inputs ----
    const float2* P2 = (const float2*)P + (size_t)gi * 3;
    const float2* U2 = (const float2*)U + (size_t)gi * 3;
    const float2* F2 = (const float2*)F + (size_t)gi * 3;
    float2 Pa = P2[0], Pb = P2[1], Pc = P2[2];
    float2 Ua = U2[0], Ub = U2[1], Uc = U2[2];
    float2 Fa = F2[0], Fb = F2[1], Fc = F2[2];
    float cm = cmax[gi];
    float cn = cmin[gi];

    bool flip = Pb.y > Pb.x;
    float fe[20];
    fe[0]  = flip ?  Pa.y :  Pa.x;
    fe[1]  = flip ?  Pa.x :  Pa.y;
    fe[2]  = flip ?  Pb.y :  Pb.x;
    fe[3]  = flip ?  Pb.x :  Pb.y;
    fe[4]  = flip ? -Pc.y :  Pc.x;
    fe[5]  = flip ? -Pc.x :  Pc.y;
    fe[6]  = flip ?  Ua.y :  Ua.x;
    fe[7]  = flip ?  Ua.x :  Ua.y;
    fe[8]  = flip ?  Ub.y :  Ub.x;
    fe[9]  = flip ?  Ub.x :  Ub.y;
    fe[10] = flip ? -Uc.y :  Uc.x;
    fe[11] = flip ? -Uc.x :  Uc.y;
    fe[12] = flip ? -Fa.y :  Fa.x;
    fe[13] = flip ? -Fa.x :  Fa.y;
    fe[14] = flip ? -Fb.y :  Fb.x;
    fe[15] = flip ? -Fb.x :  Fb.y;
    fe[16] = flip ?  Fc.y :  Fc.x;
    fe[17] = flip ?  Fc.x :  Fc.y;
    fe[18] = cm;
    fe[19] = cn;

    if (list_id == 3) {
        // trivial: cont -> HLLE, else (vacuum) -> 0
        double dd0 = fabs((double)fe[1] - (double)fe[0]);
        double dd1 = fabs((double)fe[3] - (double)fe[2]);
        double dd2 = fabs((double)fe[5] - (double)fe[4]);
        bool cont = fmax(fmax(dd0, dd1), dd2) < 0.005;
        float inv = __builtin_amdgcn_rcpf(cm - cn);
        float cmn = cm * cn;
        float f0 = cont ? (cm * fe[12] - cn * fe[13] + cmn * (fe[7]  - fe[6]))  * inv : 0.0f;
        float f1 = cont ? (cm * fe[14] - cn * fe[15] + cmn * (fe[9]  - fe[8]))  * inv : 0.0f;
        float f2 = cont ? (cm * fe[16] - cn * fe[17] + cmn * (fe[11] - fe[10])) * inv : 0.0f;
        if (flip) { f0 = -f0; f1 = -f1; }
        if (valid) {
            out[(size_t)gi * 3 + 0] = f0;
            out[(size_t)gi * 3 + 1] = f1;
            out[(size_t)gi * 3 + 2] = f2;
        }
        return;
    }

    // ---- split bf16 packing ----
    uint32_t pkh[10], pkl[10];
#pragma unroll
    for (int q = 0; q < 10; ++q) {
        float f0 = fe[2 * q], f1 = fe[2 * q + 1];
        uint32_t h0 = bf16_rne(f0), h1 = bf16_rne(f1);
        uint32_t l0 = bf16_rne(f0 - bf16_f32(h0));
        uint32_t l1 = bf16_rne(f1 - bf16_f32(h1));
        pkh[q] = h0 | (h1 << 16);
        pkl[q] = l0 | (l1 << 16);
    }

    uint32_t* row = lds_buf[wv][lane];
    // stage hi
    *(uint4*)(row)      = make_uint4(pkh[0], pkh[1], pkh[2], pkh[3]);
    *(uint4*)(row + 4)  = make_uint4(pkh[4], pkh[5], pkh[6], pkh[7]);
    *(uint4*)(row + 8)  = make_uint4(pkh[8], pkh[9], 0u, 0u);
    *(uint4*)(row + 12) = make_uint4(0u, 0u, 0u, 0u);
    __syncthreads();
    bf16x8 bfh[4];
#pragma unroll
    for (int Ct = 0; Ct < 4; ++Ct)
        bfh[Ct] = *(const bf16x8*)((const char*)lds_buf[wv][lo16 + 16 * Ct] + hi * 16);
    __syncthreads();
    // stage lo (reuse buffer)
    *(uint4*)(row)      = make_uint4(pkl[0], pkl[1], pkl[2], pkl[3]);
    *(uint4*)(row + 4)  = make_uint4(pkl[4], pkl[5], pkl[6], pkl[7]);
    *(uint4*)(row + 8)  = make_uint4(pkl[8], pkl[9], 0u, 0u);
    *(uint4*)(row + 12) = make_uint4(0u, 0u, 0u, 0u);
    __syncthreads();
    bf16x8 bfl[4];
#pragma unroll
    for (int Ct = 0; Ct < 4; ++Ct)
        bfl[Ct] = *(const bf16x8*)((const char*)lds_buf[wv][lo16 + 16 * Ct] + hi * 16);

    // ---- single-model weights ----
    int m = list_id;
    const float* b1 = (m == 0) ? b1_ds : (m == 1) ? b1_dr : b1_rs;
    const float* W2 = (m == 0) ? W2_ds : (m == 1) ? W2_dr : W2_rs;
    const float* b2 = (m == 0) ? b2_ds : (m == 1) ? b2_dr : b2_rs;

    bf16x8 afh[4], afl[4];
    f32x4 b1v[4];
    float w2v[4][12];
#pragma unroll
    for (int Ht = 0; Ht < 4; ++Ht) {
        size_t idx = (size_t)((m * 4 + Ht) * 64 + lane);
        afh[Ht] = __builtin_bit_cast(bf16x8, ((const uint4*)wf)[idx]);
        afl[Ht] = __builtin_bit_cast(bf16x8, ((const uint4*)(wf + 3072))[idx]);
        b1v[Ht] = *(const f32x4*)(b1 + 16 * Ht + 4 * hi);
        const float* w2p = W2 + (16 * Ht + 4 * hi) * 3;
        *(float4*)&w2v[Ht][0] = *(const float4*)(w2p);
        *(float4*)&w2v[Ht][4] = *(const float4*)(w2p + 4);
        *(float4*)&w2v[Ht][8] = *(const float4*)(w2p + 8);
    }

    float out_acc[4][3];
#pragma unroll
    for (int Ct = 0; Ct < 4; ++Ct) {
        f32x4 acc[4];
#pragma unroll
        for (int Ht = 0; Ht < 4; ++Ht) acc[Ht] = b1v[Ht];
#pragma unroll
        for (int Ht = 0; Ht < 4; ++Ht)
            acc[Ht] = __builtin_amdgcn_mfma_f32_16x16x32_bf16(afh[Ht], bfh[Ct], acc[Ht], 0, 0, 0);
#pragma unroll
        for (int Ht = 0; Ht < 4; ++Ht)
            acc[Ht] = __builtin_amdgcn_mfma_f32_16x16x32_bf16(afh[Ht], bfl[Ct], acc[Ht], 0, 0, 0);
#pragma unroll
        for (int Ht = 0; Ht < 4; ++Ht)
            acc[Ht] = __builtin_amdgcn_mfma_f32_16x16x32_bf16(afl[Ht], bfh[Ct], acc[Ht], 0, 0, 0);
        float s0 = 0.f, s1 = 0.f, s2 = 0.f;
#pragma unroll
        for (int Ht = 0; Ht < 4; ++Ht) {
            float q0 = 0.f, q1 = 0.f, q2 = 0.f;
#pragma unroll
            for (int r = 0; r < 4; ++r) {
                float tv = tanh_fast(acc[Ht][r]);
                q0 = fmaf(tv, w2v[Ht][r * 3 + 0], q0);
                q1 = fmaf(tv, w2v[Ht][r * 3 + 1], q1);
                q2 = fmaf(tv, w2v[Ht][r * 3 + 2], q2);
            }
            s0 += q0; s1 += q1; s2 += q2;
        }
        out_acc[Ct][0] = s0; out_acc[Ct][1] = s1; out_acc[Ct][2] = s2;
    }

    // ---- butterfly over hi-groups, pick own cell-tile ----
#pragma unroll
    for (int Ct = 0; Ct < 4; ++Ct) {
#pragma unroll
        for (int o = 0; o < 3; ++o) {
            float v = out_acc[Ct][o];
            v += __shfl_xor(v, 16);
            v += __shfl_xor(v, 32);
            out_acc[Ct][o] = v;
        }
    }
    float f0 = sel4(out_acc[0][0], out_acc[1][0], out_acc[2][0], out_acc[3][0], hi) + b2[0];
    float f1 = sel4(out_acc[0][1], out_acc[1][1], out_acc[2][1], out_acc[3][1], hi) + b2[1];
    float f2 = sel4(out_acc[0][2], out_acc[1][2], out_acc[2][2], out_acc[3][2], hi) + b2[2];

    if (flip) { f0 = -f0; f1 = -f1; }

    if (valid) {
        out[(size_t)gi * 3 + 0] = f0;
        out[(size_t)gi * 3 + 1] = f1;
        out[(size_t)gi * 3 + 2] = f2;
    }
}

extern "C" void kernel_launch(void* const* d_in, const int* in_sizes, int n_in,
                              void* d_out, int out_size, void* d_ws, size_t ws_size,
                              hipStream_t stream) {
    const float* P     = (const float*)d_in[0];
    const float* U     = (const float*)d_in[1];
    const float* F     = (const float*)d_in[2];
    const float* cmax  = (const float*)d_in[3];
    const float* cmin  = (const float*)d_in[4];
    const float* W1_ds = (const float*)d_in[5];
    const float* b1_ds = (const float*)d_in[6];
    const float* W2_ds = (const float*)d_in[7];
    const float* b2_ds = (const float*)d_in[8];
    const float* W1_dr = (const float*)d_in[9];
    const float* b1_dr = (const float*)d_in[10];
    const float* W2_dr = (const float*)d_in[11];
    const float* b2_dr = (const float*)d_in[12];
    const float* W1_rs = (const float*)d_in[13];
    const float* b1_rs = (const float*)d_in[14];
    const float* W2_rs = (const float*)d_in[15];
    const float* b2_rs = (const float*)d_in[16];

    int N = in_sizes[3];
    float* out = (float*)d_out;

    // ws layout: [0, 24576) W1 frags; [24576, 24592) counters; [32768, +16MB) lists
    uint32_t* wf   = (uint32_t*)d_ws;
    int* counters  = (int*)((char*)d_ws + 24576);
    int* lists     = (int*)((char*)d_ws + 32768);

    hipMemsetAsync(counters, 0, 16, stream);
    hipLaunchKernelGGL(prep_kernel, dim3(3), dim3(256), 0, stream,
                       W1_ds, W1_dr, W1_rs, wf);

    int nblk = (N + 255) / 256;
    hipLaunchKernelGGL(pass1_classify, dim3(nblk), dim3(256), 0, stream,
                       P, counters, lists, N);

    hipLaunchKernelGGL(pass2_mlp, dim3(nblk + 4), dim3(256), 0, stream,
                       P, U, F, cmax, cmin,
                       b1_ds, W2_ds, b2_ds,
                       b1_dr, W2_dr, b2_dr,
                       b1_rs, W2_rs, b2_rs,
                       wf, counters, lists, out, N);
}

// Round 8
// 275.718 us; speedup vs baseline: 2.7293x; 2.7293x over previous
//
#include <hip/hip_runtime.h>
#include <cstdint>

typedef __attribute__((ext_vector_type(8))) short bf16x8;
typedef __attribute__((ext_vector_type(4))) float f32x4;

__device__ __forceinline__ uint32_t bf16_rne(float f) {
    uint32_t u = __float_as_uint(f);
    u += 0x7FFFu + ((u >> 16) & 1u);
    return u >> 16;
}
__device__ __forceinline__ float bf16_f32(uint32_t h) {
    return __uint_as_float(h << 16);
}

__device__ __forceinline__ float tanh_fast(float x) {
    float e = __builtin_amdgcn_exp2f(x * 2.8853900817779268f);
    return fmaf(-2.0f, __builtin_amdgcn_rcpf(e + 1.0f), 1.0f);
}

__device__ __forceinline__ float sel4(float a, float b, float c, float d, int T) {
    float x = (T & 1) ? b : a;
    float y = (T & 1) ? d : c;
    return (T & 2) ? y : x;
}
__device__ __forceinline__ int sel4i(int a, int b, int c, int d, int T) {
    int x = (T & 1) ? b : a;
    int y = (T & 1) ? d : c;
    return (T & 2) ? y : x;
}

// ---- prep: W1 (20x64 k-major) -> MFMA A-frag layout, split bf16 hi+lo ----
__global__ __launch_bounds__(256) void prep_kernel(
    const float* __restrict__ W1_0, const float* __restrict__ W1_1,
    const float* __restrict__ W1_2, uint32_t* __restrict__ wf) {
    int m = blockIdx.x;
    const float* W1 = (m == 0) ? W1_0 : (m == 1) ? W1_1 : W1_2;
    int tid = threadIdx.x;
    int Ht = tid >> 6, lane = tid & 63;
    int n = (lane & 15) + 16 * Ht;
    int kb = (lane >> 4) * 8;
    uint32_t dh[4], dl[4];
#pragma unroll
    for (int q = 0; q < 4; ++q) {
        int k0 = kb + 2 * q, k1 = k0 + 1;
        float w0 = (k0 < 20) ? W1[k0 * 64 + n] : 0.0f;
        float w1 = (k1 < 20) ? W1[k1 * 64 + n] : 0.0f;
        uint32_t h0 = bf16_rne(w0), h1 = bf16_rne(w1);
        uint32_t l0 = bf16_rne(w0 - bf16_f32(h0));
        uint32_t l1 = bf16_rne(w1 - bf16_f32(h1));
        dh[q] = h0 | (h1 << 16);
        dl[q] = l0 | (l1 << 16);
    }
    size_t idx = ((size_t)(m * 4 + Ht) * 64 + lane) * 4;
    *(uint4*)(wf + idx)        = make_uint4(dh[0], dh[1], dh[2], dh[3]);
    *(uint4*)(wf + 3072 + idx) = make_uint4(dl[0], dl[1], dl[2], dl[3]);
}

__global__ __launch_bounds__(256, 3) void riemann_fused(
    const float* __restrict__ P, const float* __restrict__ U,
    const float* __restrict__ F, const float* __restrict__ cmax,
    const float* __restrict__ cmin,
    const float* __restrict__ b1_ds, const float* __restrict__ W2_ds, const float* __restrict__ b2_ds,
    const float* __restrict__ b1_dr, const float* __restrict__ W2_dr, const float* __restrict__ b2_dr,
    const float* __restrict__ b1_rs, const float* __restrict__ W2_rs, const float* __restrict__ b2_rs,
    const uint32_t* __restrict__ wf,
    float* __restrict__ out, int N) {
    __shared__ __align__(16) uint32_t sm_feats[256][20];  // hi then lo staged; aliased as flux later
    __shared__ int sm_perm[256];
    __shared__ int sm_labs[256];
    __shared__ int sm_cnt[4];
    __shared__ int sm_alloc[4];

    int tid = threadIdx.x;
    int wv = tid >> 6, lane = tid & 63;
    int hi = lane >> 4, lo16 = lane & 15;
    int cell = blockIdx.x * 256 + tid;
    bool valid = cell < N;
    int cg = valid ? cell : N - 1;

    // ---- per-cell prologue (identical to verified round 6) ----
    const float2* P2 = (const float2*)P + (size_t)cg * 3;
    const float2* U2 = (const float2*)U + (size_t)cg * 3;
    const float2* F2 = (const float2*)F + (size_t)cg * 3;
    float2 Pa = P2[0], Pb = P2[1], Pc = P2[2];
    float2 Ua = U2[0], Ub = U2[1], Uc = U2[2];
    float2 Fa = F2[0], Fb = F2[1], Fc = F2[2];
    float cm = cmax[cg];
    float cn = cmin[cg];

    bool flip = Pb.y > Pb.x;
    float fe[20];
    fe[0]  = flip ?  Pa.y :  Pa.x;
    fe[1]  = flip ?  Pa.x :  Pa.y;
    fe[2]  = flip ?  Pb.y :  Pb.x;
    fe[3]  = flip ?  Pb.x :  Pb.y;
    fe[4]  = flip ? -Pc.y :  Pc.x;
    fe[5]  = flip ? -Pc.x :  Pc.y;
    fe[6]  = flip ?  Ua.y :  Ua.x;
    fe[7]  = flip ?  Ua.x :  Ua.y;
    fe[8]  = flip ?  Ub.y :  Ub.x;
    fe[9]  = flip ?  Ub.x :  Ub.y;
    fe[10] = flip ? -Uc.y :  Uc.x;
    fe[11] = flip ? -Uc.x :  Uc.y;
    fe[12] = flip ? -Fa.y :  Fa.x;
    fe[13] = flip ? -Fa.x :  Fa.y;
    fe[14] = flip ? -Fb.y :  Fb.x;
    fe[15] = flip ? -Fb.x :  Fb.y;
    fe[16] = flip ?  Fc.y :  Fc.x;
    fe[17] = flip ?  Fc.x :  Fc.y;
    fe[18] = cm;
    fe[19] = cn;

    // cont: exact f64 compares
    double dd0 = fabs((double)fe[1] - (double)fe[0]);
    double dd1 = fabs((double)fe[3] - (double)fe[2]);
    double dd2 = fabs((double)fe[5] - (double)fe[4]);
    bool cont = fmax(fmax(dd0, dd1), dd2) < 0.005;

    // HLLE
    float inv = __builtin_amdgcn_rcpf(cm - cn);
    float cmn = cm * cn;
    float hl0 = (cm * fe[12] - cn * fe[13] + cmn * (fe[7]  - fe[6]))  * inv;
    float hl1 = (cm * fe[14] - cn * fe[15] + cmn * (fe[9]  - fe[8]))  * inv;
    float hl2 = (cm * fe[16] - cn * fe[17] + cmn * (fe[11] - fe[10])) * inv;

    // classification: f32 fast path + eps-guarded exact f64 fallback
    float c0f = __builtin_amdgcn_sqrtf(1.6666666f * fe[2] * __builtin_amdgcn_rcpf(fe[0]));
    float c1f = __builtin_amdgcn_sqrtf(1.6666666f * fe[3] * __builtin_amdgcn_rcpf(fe[1]));
    float dvf = fe[5] - fe[4];
    float numf = c0f + c1f - (1.0f / 3.0f) * dvf;
    float pz0 = __builtin_amdgcn_exp2f(-0.2f * __builtin_amdgcn_logf(fe[2]));
    float pz1 = __builtin_amdgcn_exp2f(-0.2f * __builtin_amdgcn_logf(fe[3]));
    float denf = c0f * pz0 + c1f * pz1;
    float tq = fmaxf(numf * __builtin_amdgcn_rcpf(denf), 1e-8f);
    float t2 = tq * tq;
    float psf = t2 * t2 * tq;
    float pminf = fminf(fe[2], fe[3]);
    float pmaxf = fmaxf(fe[2], fe[3]);
    float csum3 = 3.0f * (c0f + c1f);
    float vs = dvf - csum3;
    int label = (vs >= 0.0f) ? 3 : (psf < pminf ? 1 : (psf > pmaxf ? 0 : 2));

    const float eps = 2e-4f;
    bool amb = (fabsf(psf - pminf) <= eps * pminf) ||
               (fabsf(psf - pmaxf) <= eps * pmaxf) ||
               (fabsf(vs) <= eps * (fabsf(dvf) + csum3));
    if (__builtin_expect(amb, 0)) {
        double rho0 = (double)fe[0], rho1 = (double)fe[1];
        double p0   = (double)fe[2], p1   = (double)fe[3];
        double v0   = (double)fe[4], v1   = (double)fe[5];
        const double g = 5.0 / 3.0;
        double c0 = sqrt(g * p0 / rho0);
        double c1 = sqrt(g * p1 / rho1);
        double dv = v1 - v0;
        double z = (g - 1.0) / (2.0 * g);
        double num = c0 + c1 - 0.5 * (g - 1.0) * dv;
        double den = c0 / pow(p0, z) + c1 / pow(p1, z);
        double ps = pow(fmax(num / den, 1e-8), 1.0 / z);
        bool vacd = dv >= 2.0 / (g - 1.0) * (c0 + c1);
        label = vacd ? 3 : (ps < fmin(p0, p1) ? 1 : (ps > fmax(p0, p1) ? 0 : 2));
    }
    // work-label: 3 = trivial (cont override or vacuum) -> no MLP needed
    int wl = (!valid || cont || label == 3) ? 3 : label;

    // ---- block-local bucket sort (LDS atomics only) ----
    if (tid < 4) sm_cnt[tid] = 0;
    __syncthreads();
    atomicAdd(&sm_cnt[wl], 1);
    __syncthreads();
    if (tid == 0) {
        int s = 0;
#pragma unroll
        for (int l = 0; l < 4; ++l) { sm_alloc[l] = s; s += sm_cnt[l]; }
    }
    __syncthreads();
    int slot = atomicAdd(&sm_alloc[wl], 1);
    sm_perm[slot] = tid;
    sm_labs[slot] = wl;

    // ---- split bf16 packing ----
    uint32_t pkh[10], pkl[10];
#pragma unroll
    for (int q = 0; q < 10; ++q) {
        float f0 = fe[2 * q], f1 = fe[2 * q + 1];
        uint32_t h0 = bf16_rne(f0), h1 = bf16_rne(f1);
        uint32_t l0 = bf16_rne(f0 - bf16_f32(h0));
        uint32_t l1 = bf16_rne(f1 - bf16_f32(h1));
        pkh[q] = h0 | (h1 << 16);
        pkl[q] = l0 | (l1 << 16);
    }
    uint32_t* row = sm_feats[tid];
    // stage hi
    *(uint4*)(row)      = make_uint4(pkh[0], pkh[1], pkh[2], pkh[3]);
    *(uint4*)(row + 4)  = make_uint4(pkh[4], pkh[5], pkh[6], pkh[7]);
    *(uint4*)(row + 8)  = make_uint4(pkh[8], pkh[9], 0u, 0u);
    *(uint4*)(row + 12) = make_uint4(0u, 0u, 0u, 0u);
    __syncthreads();

    // B-frags of permuted slots (wave processes its own 64 permuted slots)
    int pslot[4], lbl[4];
    bf16x8 bfh[4], bfl[4];
#pragma unroll
    for (int Ct = 0; Ct < 4; ++Ct) {
        int s = wv * 64 + lo16 + 16 * Ct;
        pslot[Ct] = sm_perm[s];
        lbl[Ct]   = sm_labs[s];
        bfh[Ct] = *(const bf16x8*)((const char*)sm_feats[pslot[Ct]] + hi * 16);
    }
    __syncthreads();
    // stage lo (reuse buffer)
    *(uint4*)(row)      = make_uint4(pkl[0], pkl[1], pkl[2], pkl[3]);
    *(uint4*)(row + 4)  = make_uint4(pkl[4], pkl[5], pkl[6], pkl[7]);
    *(uint4*)(row + 8)  = make_uint4(pkl[8], pkl[9], 0u, 0u);
    *(uint4*)(row + 12) = make_uint4(0u, 0u, 0u, 0u);
    __syncthreads();
#pragma unroll
    for (int Ct = 0; Ct < 4; ++Ct)
        bfl[Ct] = *(const bf16x8*)((const char*)sm_feats[pslot[Ct]] + hi * 16);

    int mylab = sel4i(lbl[0], lbl[1], lbl[2], lbl[3], hi);  // lab of slot wv*64+lane

    float out_acc[4][3];
#pragma unroll
    for (int Ct = 0; Ct < 4; ++Ct) { out_acc[Ct][0] = 0.f; out_acc[Ct][1] = 0.f; out_acc[Ct][2] = 0.f; }

#pragma unroll 1
    for (int m = 0; m < 3; ++m) {
        if (__ballot(mylab == m) == 0ull) continue;   // wave-uniform model skip
        const float* b1 = (m == 0) ? b1_ds : (m == 1) ? b1_dr : b1_rs;
        const float* W2 = (m == 0) ? W2_ds : (m == 1) ? W2_dr : W2_rs;

        bf16x8 afh[4], afl[4];
        f32x4 b1v[4];
        float w2v[4][12];
#pragma unroll
        for (int Ht = 0; Ht < 4; ++Ht) {
            size_t idx = (size_t)((m * 4 + Ht) * 64 + lane);
            afh[Ht] = __builtin_bit_cast(bf16x8, ((const uint4*)wf)[idx]);
            afl[Ht] = __builtin_bit_cast(bf16x8, ((const uint4*)(wf + 3072))[idx]);
            b1v[Ht] = *(const f32x4*)(b1 + 16 * Ht + 4 * hi);
            const float* w2p = W2 + (16 * Ht + 4 * hi) * 3;
            *(float4*)&w2v[Ht][0] = *(const float4*)(w2p);
            *(float4*)&w2v[Ht][4] = *(const float4*)(w2p + 4);
            *(float4*)&w2v[Ht][8] = *(const float4*)(w2p + 8);
        }
#pragma unroll 1
        for (int Ct = 0; Ct < 4; ++Ct) {
            if (__ballot(lbl[Ct] == m) == 0ull) continue;  // Ct-tile skip
            f32x4 acc[4];
#pragma unroll
            for (int Ht = 0; Ht < 4; ++Ht) acc[Ht] = b1v[Ht];
#pragma unroll
            for (int Ht = 0; Ht < 4; ++Ht)
                acc[Ht] = __builtin_amdgcn_mfma_f32_16x16x32_bf16(afh[Ht], bfh[Ct], acc[Ht], 0, 0, 0);
#pragma unroll
            for (int Ht = 0; Ht < 4; ++Ht)
                acc[Ht] = __builtin_amdgcn_mfma_f32_16x16x32_bf16(afh[Ht], bfl[Ct], acc[Ht], 0, 0, 0);
#pragma unroll
            for (int Ht = 0; Ht < 4; ++Ht)
                acc[Ht] = __builtin_amdgcn_mfma_f32_16x16x32_bf16(afl[Ht], bfh[Ct], acc[Ht], 0, 0, 0);
            float p0 = 0.f, p1 = 0.f, p2 = 0.f;
#pragma unroll
            for (int Ht = 0; Ht < 4; ++Ht) {
#pragma unroll
                for (int r = 0; r < 4; ++r) {
                    float tv = tanh_fast(acc[Ht][r]);
                    p0 = fmaf(tv, w2v[Ht][r * 3 + 0], p0);
                    p1 = fmaf(tv, w2v[Ht][r * 3 + 1], p1);
                    p2 = fmaf(tv, w2v[Ht][r * 3 + 2], p2);
                }
            }
            float sel = (lbl[Ct] == m) ? 1.0f : 0.0f;
            out_acc[Ct][0] = fmaf(sel, p0, out_acc[Ct][0]);
            out_acc[Ct][1] = fmaf(sel, p1, out_acc[Ct][1]);
            out_acc[Ct][2] = fmaf(sel, p2, out_acc[Ct][2]);
        }
    }

    // ---- butterfly over hi-groups, pick own permuted slot ----
#pragma unroll
    for (int Ct = 0; Ct < 4; ++Ct) {
#pragma unroll
        for (int o = 0; o < 3; ++o) {
            float v = out_acc[Ct][o];
            v += __shfl_xor(v, 16);
            v += __shfl_xor(v, 32);
            out_acc[Ct][o] = v;
        }
    }
    float g0 = sel4(out_acc[0][0], out_acc[1][0], out_acc[2][0], out_acc[3][0], hi);
    float g1 = sel4(out_acc[0][1], out_acc[1][1], out_acc[2][1], out_acc[3][1], hi);
    float g2 = sel4(out_acc[0][2], out_acc[1][2], out_acc[2][2], out_acc[3][2], hi);

    // lane holds flux of permuted slot (wv*64+lane); route back to original thread
    int orig = sel4i(pslot[0], pslot[1], pslot[2], pslot[3], hi);  // = sm_perm[tid]
    __syncthreads();          // all feats reads done -> safe to alias as flux
    float (*sm_flux)[3] = (float (*)[3])sm_feats;
    sm_flux[orig][0] = g0;
    sm_flux[orig][1] = g1;
    sm_flux[orig][2] = g2;
    __syncthreads();

    float f0, f1, f2;
    if (wl < 3) {
        float bb0 = (wl == 0) ? b2_ds[0] : (wl == 1) ? b2_dr[0] : b2_rs[0];
        float bb1 = (wl == 0) ? b2_ds[1] : (wl == 1) ? b2_dr[1] : b2_rs[1];
        float bb2 = (wl == 0) ? b2_ds[2] : (wl == 1) ? b2_dr[2] : b2_rs[2];
        f0 = sm_flux[tid][0] + bb0;
        f1 = sm_flux[tid][1] + bb1;
        f2 = sm_flux[tid][2] + bb2;
    } else {
        f0 = cont ? hl0 : 0.0f;
        f1 = cont ? hl1 : 0.0f;
        f2 = cont ? hl2 : 0.0f;
    }
    if (flip) { f0 = -f0; f1 = -f1; }

    if (valid) {
        out[(size_t)cell * 3 + 0] = f0;
        out[(size_t)cell * 3 + 1] = f1;
        out[(size_t)cell * 3 + 2] = f2;
    }
}

extern "C" void kernel_launch(void* const* d_in, const int* in_sizes, int n_in,
                              void* d_out, int out_size, void* d_ws, size_t ws_size,
                              hipStream_t stream) {
    const float* P     = (const float*)d_in[0];
    const float* U     = (const float*)d_in[1];
    const float* F     = (const float*)d_in[2];
    const float* cmax  = (const float*)d_in[3];
    const float* cmin  = (const float*)d_in[4];
    const float* W1_ds = (const float*)d_in[5];
    const float* b1_ds = (const float*)d_in[6];
    const float* W2_ds = (const float*)d_in[7];
    const float* b2_ds = (const float*)d_in[8];
    const float* W1_dr = (const float*)d_in[9];
    const float* b1_dr = (const float*)d_in[10];
    const float* W2_dr = (const float*)d_in[11];
    const float* b2_dr = (const float*)d_in[12];
    const float* W1_rs = (const float*)d_in[13];
    const float* b1_rs = (const float*)d_in[14];
    const float* W2_rs = (const float*)d_in[15];
    const float* b2_rs = (const float*)d_in[16];

    int N = in_sizes[3];
    float* out = (float*)d_out;
    uint32_t* wf = (uint32_t*)d_ws;   // 24 KB: hi 12 KB + lo 12 KB

    hipLaunchKernelGGL(prep_kernel, dim3(3), dim3(256), 0, stream,
                       W1_ds, W1_dr, W1_rs, wf);

    dim3 block(256);
    dim3 grid((N + 255) / 256);
    hipLaunchKernelGGL(riemann_fused, grid, block, 0, stream,
                       P, U, F, cmax, cmin,
                       b1_ds, W2_ds, b2_ds,
                       b1_dr, W2_dr, b2_dr,
                       b1_rs, W2_rs, b2_rs,
                       wf, out, N);
}

// Round 9
// 225.264 us; speedup vs baseline: 3.3406x; 1.2240x over previous
//
#include <hip/hip_runtime.h>
#include <cstdint>

typedef __attribute__((ext_vector_type(8))) short bf16x8;
typedef __attribute__((ext_vector_type(4))) float f32x4;

__device__ __forceinline__ uint32_t bf16_rne(float f) {
    uint32_t u = __float_as_uint(f);
    u += 0x7FFFu + ((u >> 16) & 1u);
    return u >> 16;
}
__device__ __forceinline__ float bf16_f32(uint32_t h) {
    return __uint_as_float(h << 16);
}

__device__ __forceinline__ float tanh_fast(float x) {
    float e = __builtin_amdgcn_exp2f(x * 2.8853900817779268f);
    return fmaf(-2.0f, __builtin_amdgcn_rcpf(e + 1.0f), 1.0f);
}

__device__ __forceinline__ float sel4(float a, float b, float c, float d, int T) {
    float x = (T & 1) ? b : a;
    float y = (T & 1) ? d : c;
    return (T & 2) ? y : x;
}
__device__ __forceinline__ int sel4i(int a, int b, int c, int d, int T) {
    int x = (T & 1) ? b : a;
    int y = (T & 1) ? d : c;
    return (T & 2) ? y : x;
}

// ---- prep: W1 (20x64 k-major) -> MFMA A-frag layout, split bf16 hi+lo ----
__global__ __launch_bounds__(256) void prep_kernel(
    const float* __restrict__ W1_0, const float* __restrict__ W1_1,
    const float* __restrict__ W1_2, uint32_t* __restrict__ wf) {
    int m = blockIdx.x;
    const float* W1 = (m == 0) ? W1_0 : (m == 1) ? W1_1 : W1_2;
    int tid = threadIdx.x;
    int Ht = tid >> 6, lane = tid & 63;
    int n = (lane & 15) + 16 * Ht;
    int kb = (lane >> 4) * 8;
    uint32_t dh[4], dl[4];
#pragma unroll
    for (int q = 0; q < 4; ++q) {
        int k0 = kb + 2 * q, k1 = k0 + 1;
        float w0 = (k0 < 20) ? W1[k0 * 64 + n] : 0.0f;
        float w1 = (k1 < 20) ? W1[k1 * 64 + n] : 0.0f;
        uint32_t h0 = bf16_rne(w0), h1 = bf16_rne(w1);
        uint32_t l0 = bf16_rne(w0 - bf16_f32(h0));
        uint32_t l1 = bf16_rne(w1 - bf16_f32(h1));
        dh[q] = h0 | (h1 << 16);
        dl[q] = l0 | (l1 << 16);
    }
    size_t idx = ((size_t)(m * 4 + Ht) * 64 + lane) * 4;
    *(uint4*)(wf + idx)        = make_uint4(dh[0], dh[1], dh[2], dh[3]);
    *(uint4*)(wf + 3072 + idx) = make_uint4(dl[0], dl[1], dl[2], dl[3]);
}

__global__ __launch_bounds__(256, 3) void riemann_fused(
    const float* __restrict__ P, const float* __restrict__ U,
    const float* __restrict__ F, const float* __restrict__ cmax,
    const float* __restrict__ cmin,
    const float* __restrict__ b1_ds, const float* __restrict__ W2_ds, const float* __restrict__ b2_ds,
    const float* __restrict__ b1_dr, const float* __restrict__ W2_dr, const float* __restrict__ b2_dr,
    const float* __restrict__ b1_rs, const float* __restrict__ W2_rs, const float* __restrict__ b2_rs,
    const uint32_t* __restrict__ wf,
    float* __restrict__ out, int N) {
    __shared__ __align__(16) uint32_t sm_feats[256][20];  // hi then lo staged; aliased as flux later
    __shared__ int sm_perm[256];
    __shared__ int sm_labs[256];
    __shared__ int sm_cnt[4];
    __shared__ int sm_alloc[4];

    int tid = threadIdx.x;
    int wv = tid >> 6, lane = tid & 63;
    int hi = lane >> 4, lo16 = lane & 15;
    int cell = blockIdx.x * 256 + tid;
    bool valid = cell < N;
    int cg = valid ? cell : N - 1;

    // ---- per-cell prologue (identical to verified round 6/8) ----
    const float2* P2 = (const float2*)P + (size_t)cg * 3;
    const float2* U2 = (const float2*)U + (size_t)cg * 3;
    const float2* F2 = (const float2*)F + (size_t)cg * 3;
    float2 Pa = P2[0], Pb = P2[1], Pc = P2[2];
    float2 Ua = U2[0], Ub = U2[1], Uc = U2[2];
    float2 Fa = F2[0], Fb = F2[1], Fc = F2[2];
    float cm = cmax[cg];
    float cn = cmin[cg];

    bool flip = Pb.y > Pb.x;
    float fe[20];
    fe[0]  = flip ?  Pa.y :  Pa.x;
    fe[1]  = flip ?  Pa.x :  Pa.y;
    fe[2]  = flip ?  Pb.y :  Pb.x;
    fe[3]  = flip ?  Pb.x :  Pb.y;
    fe[4]  = flip ? -Pc.y :  Pc.x;
    fe[5]  = flip ? -Pc.x :  Pc.y;
    fe[6]  = flip ?  Ua.y :  Ua.x;
    fe[7]  = flip ?  Ua.x :  Ua.y;
    fe[8]  = flip ?  Ub.y :  Ub.x;
    fe[9]  = flip ?  Ub.x :  Ub.y;
    fe[10] = flip ? -Uc.y :  Uc.x;
    fe[11] = flip ? -Uc.x :  Uc.y;
    fe[12] = flip ? -Fa.y :  Fa.x;
    fe[13] = flip ? -Fa.x :  Fa.y;
    fe[14] = flip ? -Fb.y :  Fb.x;
    fe[15] = flip ? -Fb.x :  Fb.y;
    fe[16] = flip ?  Fc.y :  Fc.x;
    fe[17] = flip ?  Fc.x :  Fc.y;
    fe[18] = cm;
    fe[19] = cn;

    // cont: exact f64 compares
    double dd0 = fabs((double)fe[1] - (double)fe[0]);
    double dd1 = fabs((double)fe[3] - (double)fe[2]);
    double dd2 = fabs((double)fe[5] - (double)fe[4]);
    bool cont = fmax(fmax(dd0, dd1), dd2) < 0.005;

    // HLLE
    float inv = __builtin_amdgcn_rcpf(cm - cn);
    float cmn = cm * cn;
    float hl0 = (cm * fe[12] - cn * fe[13] + cmn * (fe[7]  - fe[6]))  * inv;
    float hl1 = (cm * fe[14] - cn * fe[15] + cmn * (fe[9]  - fe[8]))  * inv;
    float hl2 = (cm * fe[16] - cn * fe[17] + cmn * (fe[11] - fe[10])) * inv;

    // classification: f32 fast path + eps-guarded exact f64 fallback
    float c0f = __builtin_amdgcn_sqrtf(1.6666666f * fe[2] * __builtin_amdgcn_rcpf(fe[0]));
    float c1f = __builtin_amdgcn_sqrtf(1.6666666f * fe[3] * __builtin_amdgcn_rcpf(fe[1]));
    float dvf = fe[5] - fe[4];
    float numf = c0f + c1f - (1.0f / 3.0f) * dvf;
    float pz0 = __builtin_amdgcn_exp2f(-0.2f * __builtin_amdgcn_logf(fe[2]));
    float pz1 = __builtin_amdgcn_exp2f(-0.2f * __builtin_amdgcn_logf(fe[3]));
    float denf = c0f * pz0 + c1f * pz1;
    float tq = fmaxf(numf * __builtin_amdgcn_rcpf(denf), 1e-8f);
    float t2 = tq * tq;
    float psf = t2 * t2 * tq;
    float pminf = fminf(fe[2], fe[3]);
    float pmaxf = fmaxf(fe[2], fe[3]);
    float csum3 = 3.0f * (c0f + c1f);
    float vs = dvf - csum3;
    int label = (vs >= 0.0f) ? 3 : (psf < pminf ? 1 : (psf > pmaxf ? 0 : 2));

    const float eps = 2e-4f;
    bool amb = (fabsf(psf - pminf) <= eps * pminf) ||
               (fabsf(psf - pmaxf) <= eps * pmaxf) ||
               (fabsf(vs) <= eps * (fabsf(dvf) + csum3));
    if (__builtin_expect(amb, 0)) {
        double rho0 = (double)fe[0], rho1 = (double)fe[1];
        double p0   = (double)fe[2], p1   = (double)fe[3];
        double v0   = (double)fe[4], v1   = (double)fe[5];
        const double g = 5.0 / 3.0;
        double c0 = sqrt(g * p0 / rho0);
        double c1 = sqrt(g * p1 / rho1);
        double dv = v1 - v0;
        double z = (g - 1.0) / (2.0 * g);
        double num = c0 + c1 - 0.5 * (g - 1.0) * dv;
        double den = c0 / pow(p0, z) + c1 / pow(p1, z);
        double ps = pow(fmax(num / den, 1e-8), 1.0 / z);
        bool vacd = dv >= 2.0 / (g - 1.0) * (c0 + c1);
        label = vacd ? 3 : (ps < fmin(p0, p1) ? 1 : (ps > fmax(p0, p1) ? 0 : 2));
    }
    // work-label: 3 = trivial (cont override or vacuum) -> no MLP needed
    int wl = (!valid || cont || label == 3) ? 3 : label;

    // ---- block-local bucket sort (LDS atomics only) ----
    if (tid < 4) sm_cnt[tid] = 0;
    __syncthreads();
    atomicAdd(&sm_cnt[wl], 1);
    __syncthreads();
    if (tid == 0) {
        int s = 0;
#pragma unroll
        for (int l = 0; l < 4; ++l) { sm_alloc[l] = s; s += sm_cnt[l]; }
    }
    __syncthreads();
    int slot = atomicAdd(&sm_alloc[wl], 1);
    sm_perm[slot] = tid;
    sm_labs[slot] = wl;

    // ---- split bf16 packing ----
    uint32_t pkh[10], pkl[10];
#pragma unroll
    for (int q = 0; q < 10; ++q) {
        float f0 = fe[2 * q], f1 = fe[2 * q + 1];
        uint32_t h0 = bf16_rne(f0), h1 = bf16_rne(f1);
        uint32_t l0 = bf16_rne(f0 - bf16_f32(h0));
        uint32_t l1 = bf16_rne(f1 - bf16_f32(h1));
        pkh[q] = h0 | (h1 << 16);
        pkl[q] = l0 | (l1 << 16);
    }
    uint32_t* row = sm_feats[tid];
    // stage hi
    *(uint4*)(row)      = make_uint4(pkh[0], pkh[1], pkh[2], pkh[3]);
    *(uint4*)(row + 4)  = make_uint4(pkh[4], pkh[5], pkh[6], pkh[7]);
    *(uint4*)(row + 8)  = make_uint4(pkh[8], pkh[9], 0u, 0u);
    *(uint4*)(row + 12) = make_uint4(0u, 0u, 0u, 0u);
    __syncthreads();

    // B-frags of permuted slots (wave processes its own 64 permuted slots)
    int pslot0, pslot1, pslot2, pslot3;
    int lbl0, lbl1, lbl2, lbl3;
    bf16x8 bfh0, bfh1, bfh2, bfh3, bfl0, bfl1, bfl2, bfl3;
    {
        int s0 = wv * 64 + lo16;
        pslot0 = sm_perm[s0];      lbl0 = sm_labs[s0];
        pslot1 = sm_perm[s0 + 16]; lbl1 = sm_labs[s0 + 16];
        pslot2 = sm_perm[s0 + 32]; lbl2 = sm_labs[s0 + 32];
        pslot3 = sm_perm[s0 + 48]; lbl3 = sm_labs[s0 + 48];
        bfh0 = *(const bf16x8*)((const char*)sm_feats[pslot0] + hi * 16);
        bfh1 = *(const bf16x8*)((const char*)sm_feats[pslot1] + hi * 16);
        bfh2 = *(const bf16x8*)((const char*)sm_feats[pslot2] + hi * 16);
        bfh3 = *(const bf16x8*)((const char*)sm_feats[pslot3] + hi * 16);
    }
    __syncthreads();
    // stage lo (reuse buffer)
    *(uint4*)(row)      = make_uint4(pkl[0], pkl[1], pkl[2], pkl[3]);
    *(uint4*)(row + 4)  = make_uint4(pkl[4], pkl[5], pkl[6], pkl[7]);
    *(uint4*)(row + 8)  = make_uint4(pkl[8], pkl[9], 0u, 0u);
    *(uint4*)(row + 12) = make_uint4(0u, 0u, 0u, 0u);
    __syncthreads();
    bfl0 = *(const bf16x8*)((const char*)sm_feats[pslot0] + hi * 16);
    bfl1 = *(const bf16x8*)((const char*)sm_feats[pslot1] + hi * 16);
    bfl2 = *(const bf16x8*)((const char*)sm_feats[pslot2] + hi * 16);
    bfl3 = *(const bf16x8*)((const char*)sm_feats[pslot3] + hi * 16);

    int mylab = sel4i(lbl0, lbl1, lbl2, lbl3, hi);  // lab of slot wv*64+lane

    float oa00 = 0.f, oa01 = 0.f, oa02 = 0.f;
    float oa10 = 0.f, oa11 = 0.f, oa12 = 0.f;
    float oa20 = 0.f, oa21 = 0.f, oa22 = 0.f;
    float oa30 = 0.f, oa31 = 0.f, oa32 = 0.f;

#pragma unroll 1
    for (int m = 0; m < 3; ++m) {
        if (__ballot(mylab == m) == 0ull) continue;   // wave-uniform model skip
        const float* b1 = (m == 0) ? b1_ds : (m == 1) ? b1_dr : b1_rs;
        const float* W2 = (m == 0) ? W2_ds : (m == 1) ? W2_dr : W2_rs;

        bf16x8 afh[4], afl[4];
        f32x4 b1v[4];
        float w2v[4][12];
#pragma unroll
        for (int Ht = 0; Ht < 4; ++Ht) {
            size_t idx = (size_t)((m * 4 + Ht) * 64 + lane);
            afh[Ht] = __builtin_bit_cast(bf16x8, ((const uint4*)wf)[idx]);
            afl[Ht] = __builtin_bit_cast(bf16x8, ((const uint4*)(wf + 3072))[idx]);
            b1v[Ht] = *(const f32x4*)(b1 + 16 * Ht + 4 * hi);
            const float* w2p = W2 + (16 * Ht + 4 * hi) * 3;
            *(float4*)&w2v[Ht][0] = *(const float4*)(w2p);
            *(float4*)&w2v[Ht][4] = *(const float4*)(w2p + 4);
            *(float4*)&w2v[Ht][8] = *(const float4*)(w2p + 8);
        }
        // fully unrolled Ct tiles; static indexing everywhere (no scratch)
#pragma unroll
        for (int Ct = 0; Ct < 4; ++Ct) {
            int lblC = (Ct == 0) ? lbl0 : (Ct == 1) ? lbl1 : (Ct == 2) ? lbl2 : lbl3;
            if (__ballot(lblC == m) != 0ull) {
                bf16x8 bh = (Ct == 0) ? bfh0 : (Ct == 1) ? bfh1 : (Ct == 2) ? bfh2 : bfh3;
                bf16x8 bl = (Ct == 0) ? bfl0 : (Ct == 1) ? bfl1 : (Ct == 2) ? bfl2 : bfl3;
                f32x4 acc[4];
#pragma unroll
                for (int Ht = 0; Ht < 4; ++Ht) acc[Ht] = b1v[Ht];
#pragma unroll
                for (int Ht = 0; Ht < 4; ++Ht)
                    acc[Ht] = __builtin_amdgcn_mfma_f32_16x16x32_bf16(afh[Ht], bh, acc[Ht], 0, 0, 0);
#pragma unroll
                for (int Ht = 0; Ht < 4; ++Ht)
                    acc[Ht] = __builtin_amdgcn_mfma_f32_16x16x32_bf16(afh[Ht], bl, acc[Ht], 0, 0, 0);
#pragma unroll
                for (int Ht = 0; Ht < 4; ++Ht)
                    acc[Ht] = __builtin_amdgcn_mfma_f32_16x16x32_bf16(afl[Ht], bh, acc[Ht], 0, 0, 0);
                float p0 = 0.f, p1 = 0.f, p2 = 0.f;
#pragma unroll
                for (int Ht = 0; Ht < 4; ++Ht) {
#pragma unroll
                    for (int r = 0; r < 4; ++r) {
                        float tv = tanh_fast(acc[Ht][r]);
                        p0 = fmaf(tv, w2v[Ht][r * 3 + 0], p0);
                        p1 = fmaf(tv, w2v[Ht][r * 3 + 1], p1);
                        p2 = fmaf(tv, w2v[Ht][r * 3 + 2], p2);
                    }
                }
                float sel = (lblC == m) ? 1.0f : 0.0f;
                if (Ct == 0) { oa00 = fmaf(sel, p0, oa00); oa01 = fmaf(sel, p1, oa01); oa02 = fmaf(sel, p2, oa02); }
                if (Ct == 1) { oa10 = fmaf(sel, p0, oa10); oa11 = fmaf(sel, p1, oa11); oa12 = fmaf(sel, p2, oa12); }
                if (Ct == 2) { oa20 = fmaf(sel, p0, oa20); oa21 = fmaf(sel, p1, oa21); oa22 = fmaf(sel, p2, oa22); }
                if (Ct == 3) { oa30 = fmaf(sel, p0, oa30); oa31 = fmaf(sel, p1, oa31); oa32 = fmaf(sel, p2, oa32); }
            }
        }
    }

    // ---- butterfly over hi-groups, pick own permuted slot ----
#pragma unroll
    for (int o = 0; o < 1; ++o) {}  // (keep structure simple)
    {
        float* accs[12] = {&oa00, &oa01, &oa02, &oa10, &oa11, &oa12,
                           &oa20, &oa21, &oa22, &oa30, &oa31, &oa32};
#pragma unroll
        for (int q = 0; q < 12; ++q) {
            float v = *accs[q];
            v += __shfl_xor(v, 16);
            v += __shfl_xor(v, 32);
            *accs[q] = v;
        }
    }
    float g0 = sel4(oa00, oa10, oa20, oa30, hi);
    float g1 = sel4(oa01, oa11, oa21, oa31, hi);
    float g2 = sel4(oa02, oa12, oa22, oa32, hi);

    // lane holds flux of permuted slot (wv*64+lane); route back to original thread
    int orig = sel4i(pslot0, pslot1, pslot2, pslot3, hi);  // = sm_perm[wv*64+lane]
    __syncthreads();          // all feats reads done -> safe to alias as flux
    float (*sm_flux)[3] = (float (*)[3])sm_feats;
    sm_flux[orig][0] = g0;
    sm_flux[orig][1] = g1;
    sm_flux[orig][2] = g2;
    __syncthreads();

    float f0, f1, f2;
    if (wl < 3) {
        float bb0 = (wl == 0) ? b2_ds[0] : (wl == 1) ? b2_dr[0] : b2_rs[0];
        float bb1 = (wl == 0) ? b2_ds[1] : (wl == 1) ? b2_dr[1] : b2_rs[1];
        float bb2 = (wl == 0) ? b2_ds[2] : (wl == 1) ? b2_dr[2] : b2_rs[2];
        f0 = sm_flux[tid][0] + bb0;
        f1 = sm_flux[tid][1] + bb1;
        f2 = sm_flux[tid][2] + bb2;
    } else {
        f0 = cont ? hl0 : 0.0f;
        f1 = cont ? hl1 : 0.0f;
        f2 = cont ? hl2 : 0.0f;
    }
    if (flip) { f0 = -f0; f1 = -f1; }

    if (valid) {
        out[(size_t)cell * 3 + 0] = f0;
        out[(size_t)cell * 3 + 1] = f1;
        out[(size_t)cell * 3 + 2] = f2;
    }
}

extern "C" void kernel_launch(void* const* d_in, const int* in_sizes, int n_in,
                              void* d_out, int out_size, void* d_ws, size_t ws_size,
                              hipStream_t stream) {
    const float* P     = (const float*)d_in[0];
    const float* U     = (const float*)d_in[1];
    const float* F     = (const float*)d_in[2];
    const float* cmax  = (const float*)d_in[3];
    const float* cmin  = (const float*)d_in[4];
    const float* W1_ds = (const float*)d_in[5];
    const float* b1_ds = (const float*)d_in[6];
    const float* W2_ds = (const float*)d_in[7];
    const float* b2_ds = (const float*)d_in[8];
    const float* W1_dr = (const float*)d_in[9];
    const float* b1_dr = (const float*)d_in[10];
    const float* W2_dr = (const float*)d_in[11];
    const float* b2_dr = (const float*)d_in[12];
    const float* W1_rs = (const float*)d_in[13];
    const float* b1_rs = (const float*)d_in[14];
    const float* W2_rs = (const float*)d_in[15];
    const float* b2_rs = (const float*)d_in[16];

    int N = in_sizes[3];
    float* out = (float*)d_out;
    uint32_t* wf = (uint32_t*)d_ws;   // 24 KB: hi 12 KB + lo 12 KB

    hipLaunchKernelGGL(prep_kernel, dim3(3), dim3(256), 0, stream,
                       W1_ds, W1_dr, W1_rs, wf);

    dim3 block(256);
    dim3 grid((N + 255) / 256);
    hipLaunchKernelGGL(riemann_fused, grid, block, 0, stream,
                       P, U, F, cmax, cmin,
                       b1_ds, W2_ds, b2_ds,
                       b1_dr, W2_dr, b2_dr,
                       b1_rs, W2_rs, b2_rs,
                       wf, out, N);
}